// Round 4
// baseline (151.156 us; speedup 1.0000x reference)
//
#include <hip/hip_runtime.h>

typedef unsigned short u16;
typedef __attribute__((ext_vector_type(8))) short bf16x8;          // MFMA A/B frag
typedef __attribute__((ext_vector_type(8))) unsigned short u16x8;  // 8 bf16 load
typedef __attribute__((ext_vector_type(4))) float f32x4;           // MFMA C/D frag

#define WPB   4
#define BLOCK (WPB * 64)

__device__ __forceinline__ float bf2f(u16 u) {
    union { unsigned i; float f; } v; v.i = (unsigned)u << 16; return v.f;
}
__device__ __forceinline__ u16 f2bf(float f) {   // RNE
    union { float f; unsigned u; } v; v.f = f;
    unsigned r = v.u + 0x7fff + ((v.u >> 16) & 1);
    return (u16)(r >> 16);
}

// prep: feats f32 -> bf16 rows; kmat f32 [k=s*64+c][n] -> ready MFMA B-fragments
__global__ __launch_bounds__(256)
void prep_kernel(const float* __restrict__ feats, const float* __restrict__ kmat,
                 u16* __restrict__ fbf, u16* __restrict__ kbg, int nfeat8) {
    const int id = blockIdx.x * 256 + threadIdx.x;
    if (id < nfeat8) {
        const float4 a = ((const float4*)feats)[2 * id];
        const float4 b = ((const float4*)feats)[2 * id + 1];
        union { u16 h[8]; int4 v; } p;
        p.h[0] = f2bf(a.x); p.h[1] = f2bf(a.y); p.h[2] = f2bf(a.z); p.h[3] = f2bf(a.w);
        p.h[4] = f2bf(b.x); p.h[5] = f2bf(b.y); p.h[6] = f2bf(b.z); p.h[7] = f2bf(b.w);
        ((int4*)fbf)[id] = p.v;
    }
    if (id < 16384) {
        const int k = id >> 6, n = id & 63;
        const int nt = n >> 4, ks = k >> 5;
        const int lanep = (((k >> 3) & 3) << 4) | (n & 15), j = k & 7;
        kbg[(((((nt << 3) | ks) << 6) | lanep) << 3) | j] = f2bf(kmat[id]);
    }
}

// One wave = one 16-output tile.
//   A1 (registers): lane (m=lane&15, quad) computes edge t=quad+4u -> sph[4], idx
//   A2: per c-half h, acc[s][j] = sum_t sph_t[s] * feat[idx_t][c], c = h*32+quad*8+j
//       (idx/sph fetched cross-lane via shuffles; gather = one 16B bf16 load/lane/t)
//   B : C[nt] += afr[s] x KB[nt][2s+h]  (mfma 16x16x32 bf16), epilogue +bias
template<bool USE_WS>
__global__ __launch_bounds__(BLOCK, 3)
void sphconv_main(const float* __restrict__ featsf, const u16* __restrict__ fbf,
                  const float* __restrict__ in_pos, const float* __restrict__ out_pos,
                  const float* __restrict__ extents, const float* __restrict__ kmat,
                  const u16* __restrict__ kbg, const float* __restrict__ bias,
                  const int* __restrict__ nidx, const int* __restrict__ rsplits,
                  float* __restrict__ out, int n_out, int ntiles, int n_edges)
{
    __shared__ u16 KB[16384];   // 32 KB: [nt][ks][lane][j] bf16 B-fragments
    const int tid = threadIdx.x, wave = tid >> 6, lane = tid & 63;

    if constexpr (USE_WS) {
        const int4* s = (const int4*)kbg; int4* d = (int4*)KB;
        for (int i = tid; i < 2048; i += BLOCK) d[i] = s[i];
    } else {
        for (int i = tid; i < 16384; i += BLOCK) {
            const int k = i >> 6, n = i & 63;
            const int nt = n >> 4, ks = k >> 5;
            const int lanep = (((k >> 3) & 3) << 4) | (n & 15), j = k & 7;
            KB[(((((nt << 3) | ks) << 6) | lanep) << 3) | j] = f2bf(kmat[i]);
        }
    }
    __syncthreads();

    const int tile = blockIdx.x * WPB + wave;
    if (tile >= ntiles) return;

    const int m = lane & 15, quad = lane >> 4;
    const int obase = tile << 4;
    const int o  = obase + m;
    const int oc = min(o, n_out - 1);
    const int e0 = rsplits[oc];
    const int e1 = rsplits[oc + 1];
    const float qx = out_pos[oc * 3 + 0];
    const float qy = out_pos[oc * 3 + 1];
    const float qz = out_pos[oc * 3 + 2];
    const float inv_ext = __fdividef(1.f, extents[0]);

    // ---- A1: 16 edges of this tile spread over lanes (t = 4u + quad) ----
    float sph_r[4][4]; int idx_r[4];
    #pragma unroll
    for (int u = 0; u < 4; ++u) {
        const int t = (u << 2) | quad;
        const int e = e0 + t;
        const bool v = (o < n_out) && (e < e1);
        const int id = nidx[min(e, n_edges - 1)];
        const float dx = in_pos[id * 3 + 0] - qx;
        const float dy = in_pos[id * 3 + 1] - qy;
        const float dz = in_pos[id * 3 + 2] - qz;
        const float rp2 = dx * dx + dy * dy;
        const float r2  = rp2 + dz * dz;
        const float rs  = fmaxf(sqrtf(r2), 1e-10f);
        const float rp  = fmaxf(sqrtf(rp2), 1e-10f);
        const float ir  = __fdividef(1.f, rs);
        const float irp = __fdividef(1.f, rp);
        sph_r[u][0] = v ? rs * inv_ext : 0.f;
        sph_r[u][1] = v ? dz * ir      : 0.f;
        sph_r[u][2] = v ? dy * irp     : 0.f;
        sph_r[u][3] = v ? dx * irp     : 0.f;
        idx_r[u] = id;     // row gathered harmlessly when weights are 0
    }

    // pre-shuffle all 16 edge indices (gather addresses free of in-loop deps)
    int idx_sh[16];
    #pragma unroll
    for (int t = 0; t < 16; ++t)
        idx_sh[t] = __shfl(idx_r[t >> 2], ((t & 3) << 4) | m, 64);

    f32x4 C[4] = {{0,0,0,0},{0,0,0,0},{0,0,0,0},{0,0,0,0}};
    const bf16x8* kbp = (const bf16x8*)KB;

    #pragma unroll
    for (int h = 0; h < 2; ++h) {          // c-half: c = h*32 + quad*8 + j
        float acc[4][8];
        #pragma unroll
        for (int s = 0; s < 4; ++s)
            #pragma unroll
            for (int j = 0; j < 8; ++j) acc[s][j] = 0.f;

        #pragma unroll
        for (int t = 0; t < 16; ++t) {
            const int src = ((t & 3) << 4) | m;
            float fv[8];
            if constexpr (USE_WS) {
                const u16x8 fr = *(const u16x8*)(fbf + (idx_sh[t] << 6) + (h << 5) + (quad << 3));
                #pragma unroll
                for (int j = 0; j < 8; ++j) fv[j] = bf2f(fr[j]);
            } else {
                const float* fp = featsf + (idx_sh[t] << 6) + (h << 5) + (quad << 3);
                const float4 A0 = *(const float4*)fp;
                const float4 A1 = *(const float4*)(fp + 4);
                fv[0] = A0.x; fv[1] = A0.y; fv[2] = A0.z; fv[3] = A0.w;
                fv[4] = A1.x; fv[5] = A1.y; fv[6] = A1.z; fv[7] = A1.w;
            }
            const float s0 = __shfl(sph_r[t >> 2][0], src, 64);
            const float s1 = __shfl(sph_r[t >> 2][1], src, 64);
            const float s2 = __shfl(sph_r[t >> 2][2], src, 64);
            const float s3 = __shfl(sph_r[t >> 2][3], src, 64);
            #pragma unroll
            for (int j = 0; j < 8; ++j) {
                acc[0][j] = fmaf(s0, fv[j], acc[0][j]);
                acc[1][j] = fmaf(s1, fv[j], acc[1][j]);
                acc[2][j] = fmaf(s2, fv[j], acc[2][j]);
                acc[3][j] = fmaf(s3, fv[j], acc[3][j]);
            }
        }

        bf16x8 afr[4];
        #pragma unroll
        for (int s = 0; s < 4; ++s) {
            union { u16 hh[8]; bf16x8 v; } p;
            #pragma unroll
            for (int j = 0; j < 8; ++j) p.hh[j] = f2bf(acc[s][j]);
            afr[s] = p.v;
        }

        #pragma unroll
        for (int nt = 0; nt < 4; ++nt)
            #pragma unroll
            for (int s = 0; s < 4; ++s) {
                const bf16x8 b = kbp[(((nt << 3) | ((s << 1) | h)) << 6) | lane];
                C[nt] = __builtin_amdgcn_mfma_f32_16x16x32_bf16(afr[s], b, C[nt], 0, 0, 0);
            }
    }

    // ---- epilogue: D[m = quad*4+r][f = nt*16 + (lane&15)] ----
    #pragma unroll
    for (int nt = 0; nt < 4; ++nt) {
        const int f = (nt << 4) | m;
        const float bv = bias[f];
        #pragma unroll
        for (int r = 0; r < 4; ++r) {
            const int oo = obase + (quad << 2) + r;
            if (oo < n_out) out[(oo << 6) | f] = C[nt][r] + bv;
        }
    }
}

extern "C" void kernel_launch(void* const* d_in, const int* in_sizes, int n_in,
                              void* d_out, int out_size, void* d_ws, size_t ws_size,
                              hipStream_t stream) {
    const float* feats   = (const float*)d_in[0];
    const float* in_pos  = (const float*)d_in[1];
    const float* out_pos = (const float*)d_in[2];
    const float* extents = (const float*)d_in[3];
    const float* kmat    = (const float*)d_in[4];
    const float* bias    = (const float*)d_in[5];
    const int*   nidx    = (const int*)d_in[6];
    const int*   rsplits = (const int*)d_in[7];
    const int n_out   = in_sizes[7] - 1;
    const int n_edges = in_sizes[6];
    const int ntiles  = (n_out + 15) >> 4;
    const int grid    = (ntiles + WPB - 1) / WPB;

    const size_t fbf_bytes = (size_t)in_sizes[0] * 2;
    const size_t need = fbf_bytes + 32768;

    if (ws_size >= need) {
        u16* fbf = (u16*)d_ws;
        u16* kbg = (u16*)((char*)d_ws + fbf_bytes);
        const int nfeat8 = in_sizes[0] / 8;
        const int pmax   = nfeat8 > 16384 ? nfeat8 : 16384;
        const int pgrid  = (pmax + 255) / 256;
        prep_kernel<<<pgrid, 256, 0, stream>>>(feats, kmat, fbf, kbg, nfeat8);
        sphconv_main<true><<<grid, BLOCK, 0, stream>>>(
            feats, fbf, in_pos, out_pos, extents, kmat, kbg, bias,
            nidx, rsplits, (float*)d_out, n_out, ntiles, n_edges);
    } else {
        sphconv_main<false><<<grid, BLOCK, 0, stream>>>(
            feats, nullptr, in_pos, out_pos, extents, kmat, nullptr, bias,
            nidx, rsplits, (float*)d_out, n_out, ntiles, n_edges);
    }
}